// Round 12
// baseline (158.048 us; speedup 1.0000x reference)
//
#include <hip/hip_runtime.h>

// BahdanauAttention_16518444220431 — diagonal-DP recurrence on MI355X (gfx950).
// R12 = R11 (32-row tiles, 1024 blocks, alternating-phase, 16 intervals) with
// LDS squeezed to EXACTLY 32768 B (U buffers only): xw window + zero-chunk
// moved to a prep-built per-tile table in d_ws (L2-resident, per-lane
// global_load_dwordx4 at interval top). Theory: R11's 33792 B block missed
// the ~128-134KB workgroup-LDS pool by a hair -> stuck at 2 blocks/CU, 2
// rounds, 32 slots (x ~1.9us fixed/slot). 32768x4 = 131072 fits -> 4
// blocks/CU, 1 round, 16 slots, 16 waves/CU.
// REGISTER LEDGER (target <=128 unified for 4 waves/SIMD): acc 32 AGPR +
// w2c[2][4]=32 + w1x 8 + pk 16 + working ~35 ≈ 123. LESSONS: launch_bounds
// (256,2) only (tighter caps spill acc, R2/R3); FETCH>10MB = spill tripwire.

typedef __bf16 bf16x8 __attribute__((ext_vector_type(8)));
typedef __bf16 bf16x4 __attribute__((ext_vector_type(4)));
typedef float f32x16 __attribute__((ext_vector_type(16)));

#define MFMA32(a, b, c) __builtin_amdgcn_mfma_f32_32x32x16_bf16(a, b, c, 0, 0, 0)

__device__ __forceinline__ unsigned short f2bf(float f) {
  unsigned int u = __builtin_bit_cast(unsigned int, f);
  u += 0x7fffu + ((u >> 16) & 1u);
  return (unsigned short)(u >> 16);
}

// ws layout (bf16 elements):
//   [0,65536)        W2 fragments: ((ot*16+ks)*64+lane)*8+j ; o=ot*32+(lane&31), k=ks*16+(lane>>5)*8+j
//   [65536,131072)   W4 fragments, same permutation
//   [131072,135168)  W1-extra frags: lanes<32: j<4 -> W1[o][j], j==4 -> b1[o]+b2[o], else 0
//   [135168,139264)  W3-extra frags: j==4 -> b3[o]+2*b4[o]
//   [139264,335872)  xw table: per tile (1024? no: 512 j-tiles... here 1024 tiles of 32 rows)
//                    xwt[tile*48 + i] = [x0,x1,x2,x3,1,0,0,0] bf16 chunk for row j0-8+i
#define XW_OFF 139264
#define N_TILES 1024          // 16 batches x 64 j-tiles of 32 rows
#define PREP_TOTAL (139264 + N_TILES * 48 * 8)

__global__ void prep_kernel(const float* __restrict__ x,
                            const float* __restrict__ W1, const float* __restrict__ b1,
                            const float* __restrict__ W2, const float* __restrict__ b2,
                            const float* __restrict__ W3, const float* __restrict__ b3,
                            const float* __restrict__ W4, const float* __restrict__ b4,
                            unsigned short* __restrict__ ws) {
  int idx = blockIdx.x * 256 + threadIdx.x;
  if (idx < 139264) {
    float v = 0.0f;
    if (idx < 131072) {
      const float* W = (idx < 65536) ? W2 : W4;
      int i = idx & 65535;
      int j = i & 7, f = i >> 3;
      int lane = f & 63, slot = f >> 6;
      int ks = slot & 15, ot = slot >> 4;
      int o = ot * 32 + (lane & 31);
      int k = ks * 16 + (lane >> 5) * 8 + j;
      v = W[o * 256 + k];
    } else {
      int i = idx - 131072;
      bool first = (i < 4096);
      int ii = i & 4095;
      int j = ii & 7, f = ii >> 3;
      int lane = f & 63, ot = f >> 6;
      int o = ot * 32 + (lane & 31);
      if (lane < 32) {
        if (j < 4) v = first ? W1[o * 4 + j] : W3[o * 4 + j];
        else if (j == 4) v = first ? (b1[o] + b2[o]) : (b3[o] + 2.0f * b4[o]);
      }
    }
    ws[idx] = f2bf(v);
    return;
  }
  // xw table: one thread per (tile, i) chunk
  int c = idx - 139264;
  int ci = c & 7;          // only ci==0 thread writes the whole 16B chunk? no:
  // one thread per bf16 would be wasteful; instead: threads with ci==0 write int4.
  if (ci != 0) return;
  int chunk = c >> 3;               // tile*48 + i
  if (chunk >= N_TILES * 48) return;
  int tile = chunk / 48;
  int i = chunk - tile * 48;
  int b = tile >> 6;
  int j0 = (tile & 63) * 32;
  int j = j0 - 8 + i;
  int4 v = make_int4(0, 0, 0, 0);
  if (j >= 0 && j < 2048) {
    const float* xb = x + (b * 4) * 2048 + j;
    unsigned short h0 = f2bf(xb[0]);
    unsigned short h1 = f2bf(xb[2048]);
    unsigned short h2 = f2bf(xb[4096]);
    unsigned short h3 = f2bf(xb[6144]);
    v = make_int4((int)(h0 | ((unsigned int)h1 << 16)),
                  (int)(h2 | ((unsigned int)h3 << 16)),
                  0x00003f80, 0);   // chunk[4] = bf16(1.0) multiplies the bias row
  }
  *((int4*)(ws + XW_OFF) + chunk) = v;
}

#define NC 4  // W2 ks cached in regs; ks NC..15 streamed from L2 each interval

__global__ __launch_bounds__(256, 2)
void chain_kernel(const unsigned short* __restrict__ ws, float* __restrict__ out) {
  // U[ph], chunk-major over 32 rows: U[ph][c*32 + r]. EXACTLY 32768 B of LDS.
  __shared__ int4 U[2][32 * 32];

  const int tid = threadIdx.x;
  const int l = tid & 63;
  const int w = tid >> 6;
  const int lane31 = l & 31;
  const int khalf = l >> 5;
  const int tile = blockIdx.x;
  const int b = tile >> 6;
  const int j0 = (tile & 63) * 32;

  const int4* w2f = (const int4*)ws;
  const int4* w4f = (const int4*)(ws + 65536);
  const int4* w1xg = (const int4*)(ws + 131072);
  const int4* w3xg = (const int4*)(ws + 135168);
  const int4* xwt = (const int4*)(ws + XW_OFF) + tile * 48;

  const int ot0 = w * 2;
  bf16x8 w2c[2][NC];
  bf16x8 w1x[2];
#pragma unroll
  for (int t2 = 0; t2 < 2; ++t2) {
    w1x[t2] = __builtin_bit_cast(bf16x8, w1xg[(ot0 + t2) * 64 + l]);
#pragma unroll
    for (int ks = 0; ks < NC; ++ks)
      w2c[t2][ks] = __builtin_bit_cast(bf16x8, w2f[((ot0 + t2) * 16 + ks) * 64 + l]);
  }

  const int mrow = lane31;
  const bf16x8 bzero = {};

  uint2 pk[2][4];   // packed prev-interval results [t2][q] (16 VGPRs)

#pragma unroll 1
  for (int half = 0; half < 16; ++half) {   // half = 2*(t-1) + interval
    const int t = (half >> 1) + 1;
    const int ph = half & 1;                // GEMM phase this interval

    // ---- L2 load of this interval's a-chunk (issued early; lanes>=32 zero) ----
    int widx = (ph == 0) ? (mrow + t - 1) : (mrow + 17 - t);
    int4 bxi = xwt[widx];

    f32x16 acc[2] = {};                     // [t2] — single phase, 32 rows

    // ---- write PREVIOUS interval's packed state into the other buffer ----
    if (half > 0) {
      int4* Uw = U[ph ^ 1];
#pragma unroll
      for (int t2 = 0; t2 < 2; ++t2) {
#pragma unroll
        for (int q = 0; q < 4; ++q) {
          int idx = ((ot0 + t2) * 4 + q) * 32 + mrow;
          *(uint2*)((char*)(Uw + idx) + khalf * 8) = pk[t2][q];
        }
      }
    }

    // ---- extra K=16 step: adds a[pos] + bias ----
    {
      bf16x8 bx = (l < 32) ? __builtin_bit_cast(bf16x8, bxi) : bzero;
      acc[0] = MFMA32(w1x[0], bx, acc[0]);
      acc[1] = MFMA32(w1x[1], bx, acc[1]);
    }

    // ---- main GEMM over this phase's previous state (skip at t==1) ----
    if (t > 1) {
      const int4* Ur = U[ph];
#pragma unroll
      for (int ks = 0; ks < 16; ++ks) {
        int c0 = 2 * ks + khalf;
        bf16x8 bu = __builtin_bit_cast(bf16x8, Ur[c0 * 32 + mrow]);
        bf16x8 af0, af1;
        if (ks < NC) { af0 = w2c[0][ks]; af1 = w2c[1][ks]; }
        else {
          af0 = __builtin_bit_cast(bf16x8, w2f[(ot0 * 16 + ks) * 64 + l]);
          af1 = __builtin_bit_cast(bf16x8, w2f[((ot0 + 1) * 16 + ks) * 64 + l]);
        }
        acc[0] = MFMA32(af0, bu, acc[0]);
        acc[1] = MFMA32(af1, bu, acc[1]);
      }
    }

    // ---- relu + bf16 pack into registers (written NEXT interval) ----
#pragma unroll
    for (int t2 = 0; t2 < 2; ++t2) {
#pragma unroll
      for (int q = 0; q < 4; ++q) {
        bf16x4 h;
        h.x = (__bf16)fmaxf(acc[t2][4 * q + 0], 0.0f);
        h.y = (__bf16)fmaxf(acc[t2][4 * q + 1], 0.0f);
        h.z = (__bf16)fmaxf(acc[t2][4 * q + 2], 0.0f);
        h.w = (__bf16)fmaxf(acc[t2][4 * q + 3], 0.0f);
        pk[t2][q] = __builtin_bit_cast(uint2, h);
      }
    }
    __syncthreads();
  }

  // ---- flush last down-state (pk of half=15) -> U1 ----
  {
    int4* Uw = U[1];
#pragma unroll
    for (int t2 = 0; t2 < 2; ++t2) {
#pragma unroll
      for (int q = 0; q < 4; ++q) {
        int idx = ((ot0 + t2) * 4 + q) * 32 + mrow;
        *(uint2*)((char*)(Uw + idx) + khalf * 8) = pk[t2][q];
      }
    }
  }
  __syncthreads();

  // ---- final: miu^T = relu(W3x + b3 + 2b4 + W4*U0 + W4*U1), in-block ----
  {
    int4 bxi = xwt[mrow + 8];
    f32x16 acc[2] = {};   // [t2]
    bf16x8 w3x0 = __builtin_bit_cast(bf16x8, w3xg[ot0 * 64 + l]);
    bf16x8 w3x1 = __builtin_bit_cast(bf16x8, w3xg[(ot0 + 1) * 64 + l]);
    {
      bf16x8 bx = (l < 32) ? __builtin_bit_cast(bf16x8, bxi) : bzero;
      acc[0] = MFMA32(w3x0, bx, acc[0]);
      acc[1] = MFMA32(w3x1, bx, acc[1]);
    }
#pragma unroll 1
    for (int ph = 0; ph < 2; ++ph) {
      const int4* Sp = U[ph];
#pragma unroll
      for (int ks = 0; ks < 16; ++ks) {
        int c0 = 2 * ks + khalf;
        bf16x8 bu = __builtin_bit_cast(bf16x8, Sp[c0 * 32 + mrow]);
        bf16x8 af0 = __builtin_bit_cast(bf16x8, w4f[(ot0 * 16 + ks) * 64 + l]);
        bf16x8 af1 = __builtin_bit_cast(bf16x8, w4f[((ot0 + 1) * 16 + ks) * 64 + l]);
        acc[0] = MFMA32(af0, bu, acc[0]);
        acc[1] = MFMA32(af1, bu, acc[1]);
      }
    }
    int pbase = (b * 2048 + j0 + mrow) * 256;
#pragma unroll
    for (int t2 = 0; t2 < 2; ++t2) {
#pragma unroll
      for (int q = 0; q < 4; ++q) {
        int ob = (ot0 + t2) * 32 + 8 * q + 4 * khalf;
        float4 v;
        v.x = fmaxf(acc[t2][4 * q + 0], 0.0f);
        v.y = fmaxf(acc[t2][4 * q + 1], 0.0f);
        v.z = fmaxf(acc[t2][4 * q + 2], 0.0f);
        v.w = fmaxf(acc[t2][4 * q + 3], 0.0f);
        *(float4*)(out + pbase + ob) = v;
      }
    }
  }
}

extern "C" void kernel_launch(void* const* d_in, const int* in_sizes, int n_in,
                              void* d_out, int out_size, void* d_ws, size_t ws_size,
                              hipStream_t stream) {
  const float* x  = (const float*)d_in[0];
  const float* W1 = (const float*)d_in[1];
  const float* b1 = (const float*)d_in[2];
  const float* W2 = (const float*)d_in[3];
  const float* b2 = (const float*)d_in[4];
  const float* W3 = (const float*)d_in[5];
  const float* b3 = (const float*)d_in[6];
  const float* W4 = (const float*)d_in[7];
  const float* b4 = (const float*)d_in[8];
  unsigned short* ws = (unsigned short*)d_ws;

  prep_kernel<<<(PREP_TOTAL + 255) / 256, 256, 0, stream>>>(x, W1, b1, W2, b2, W3, b3, W4, b4, ws);
  chain_kernel<<<N_TILES, 256, 0, stream>>>(ws, (float*)d_out);
}